// Round 3
// baseline (790.041 us; speedup 1.0000x reference)
//
#include <hip/hip_runtime.h>
#include <math.h>

#define B 8
#define N 2048
#define D 1024

#define BM 128
#define BN 128
#define BK 32

typedef __bf16 bf16;
typedef __bf16 bf16x8 __attribute__((ext_vector_type(8)));
typedef __bf16 bf16x4 __attribute__((ext_vector_type(4)));
typedef float f32x4 __attribute__((ext_vector_type(4)));
typedef float f32x16 __attribute__((ext_vector_type(16)));

__device__ __forceinline__ void load_lds16(const void* g, void* l) {
    __builtin_amdgcn_global_load_lds((const __attribute__((address_space(1))) void*)g,
                                     (__attribute__((address_space(3))) void*)l, 16, 0, 0);
}

#define MFMA16(a, b, c) __builtin_amdgcn_mfma_f32_16x16x32_bf16(a, b, c, 0, 0, 0)
#define MFMA32(a, b, c) __builtin_amdgcn_mfma_f32_32x32x16_bf16(a, b, c, 0, 0, 0)
#define BARRIER() asm volatile("s_barrier" ::: "memory")
#define WAITV0() asm volatile("s_waitcnt vmcnt(0)" ::: "memory")

// ---------------------------------------------------------------------------
// Split fp32 x into bf16 hi + lo residual (hi = RN(x), lo = RN(x - hi)).
// ---------------------------------------------------------------------------
__global__ __launch_bounds__(256) void split_fp32(const float* __restrict__ x,
                                                  bf16* __restrict__ h,
                                                  bf16* __restrict__ l, long n)
{
    long i = ((long)blockIdx.x * 256 + threadIdx.x) * 4;
    if (i >= n) return;
    float4 v = *(const float4*)(x + i);
    float vs[4] = {v.x, v.y, v.z, v.w};
    bf16x4 hh, ll;
#pragma unroll
    for (int t = 0; t < 4; ++t) {
        bf16 hv = (bf16)vs[t];
        hh[t] = hv;
        ll[t] = (bf16)(vs[t] - (float)hv);
    }
    *(bf16x4*)(h + i) = hh;
    *(bf16x4*)(l + i) = ll;
}

// ---------------------------------------------------------------------------
// Transpose + split: W [1024][1024] fp32 -> WT_h/WT_l bf16, WT[d][k]=W[k][d].
// ---------------------------------------------------------------------------
__global__ __launch_bounds__(256) void tsplit_1024(const float* __restrict__ W,
                                                   bf16* __restrict__ WT_h,
                                                   bf16* __restrict__ WT_l)
{
    __shared__ float tile[64][65];
    const int d0 = blockIdx.x * 64, k0 = blockIdx.y * 64;
    const int tx = threadIdx.x & 63, ty = threadIdx.x >> 6;
#pragma unroll
    for (int r = 0; r < 16; ++r) {
        int kl = ty + r * 4;
        tile[kl][tx] = W[(size_t)(k0 + kl) * 1024 + d0 + tx];
    }
    __syncthreads();
#pragma unroll
    for (int r = 0; r < 16; ++r) {
        int dl = ty + r * 4;
        float v = tile[tx][dl];
        bf16 hv = (bf16)v;
        size_t idx = (size_t)(d0 + dl) * 1024 + k0 + tx;
        WT_h[idx] = hv;
        WT_l[idx] = (bf16)(v - (float)hv);
    }
}

// ---------------------------------------------------------------------------
// Old 128x128 NT MFMA GEMM (m97 structure) — kept ONLY for the tiny 1024^3
// Wqk product (64 small blocks for occupancy; perf-irrelevant).
// ---------------------------------------------------------------------------
template<int TERMS, int EPI>
__global__ __launch_bounds__(256) void gemm_nt_mfma(
    const bf16* __restrict__ Ah_g, const bf16* __restrict__ Al_g,
    const bf16* __restrict__ Bh_g, const bf16* __restrict__ Bl_g,
    bf16* __restrict__ Chi, bf16* __restrict__ Clo,
    float* __restrict__ Cf, const float* __restrict__ Text,
    float* __restrict__ Feat,
    int Mdim, int Ncdim, int Kdim, long sA, long sB, long sC)
{
    __shared__ bf16 Ah[BM][BK];
    __shared__ bf16 Bh[BN][BK];
    __shared__ bf16 Al[BM][BK];
    __shared__ bf16 Bl[BN][BK];

    const int tid = threadIdx.x;
    const int lane = tid & 63;
    const int wv = tid >> 6;
    const int wr = (wv >> 1) * 64;
    const int wc = (wv & 1) * 64;
    const int mfrag = lane & 15;
    const int quad = lane >> 4;

    const long z = blockIdx.z;
    const int row0 = blockIdx.y * BM;
    const int col0 = blockIdx.x * BN;

    const bf16* Abh = Ah_g + z * sA;
    const bf16* Abl = (TERMS == 3) ? (Al_g + z * sA) : nullptr;
    const bf16* Bbh = Bh_g + z * sB;
    const bf16* Bbl = (TERMS == 3) ? (Bl_g + z * sB) : nullptr;

    f32x4 acc[4][4] = {};

    for (int k0 = 0; k0 < Kdim; k0 += BK) {
#pragma unroll
        for (int q = 0; q < 2; ++q) {
            int c = q * 256 + tid;
            int row = c >> 2, kp = (c & 3) * 8;
            load_lds16(Abh + (long)(row0 + row) * Kdim + k0 + kp, &Ah[row][kp]);
            load_lds16(Bbh + (long)(col0 + row) * Kdim + k0 + kp, &Bh[row][kp]);
            if constexpr (TERMS == 3) {
                load_lds16(Abl + (long)(row0 + row) * Kdim + k0 + kp, &Al[row][kp]);
                load_lds16(Bbl + (long)(col0 + row) * Kdim + k0 + kp, &Bl[row][kp]);
            }
        }
        __syncthreads();

        bf16x8 a_h[4], b_h[4], a_l[4], b_l[4];
#pragma unroll
        for (int i = 0; i < 4; ++i) {
            a_h[i] = *(const bf16x8*)&Ah[wr + i * 16 + mfrag][quad * 8];
            b_h[i] = *(const bf16x8*)&Bh[wc + i * 16 + mfrag][quad * 8];
            if constexpr (TERMS == 3) {
                a_l[i] = *(const bf16x8*)&Al[wr + i * 16 + mfrag][quad * 8];
                b_l[i] = *(const bf16x8*)&Bl[wc + i * 16 + mfrag][quad * 8];
            }
        }
#pragma unroll
        for (int i = 0; i < 4; ++i)
#pragma unroll
            for (int j = 0; j < 4; ++j) {
                acc[i][j] = MFMA16(a_h[i], b_h[j], acc[i][j]);
                if constexpr (TERMS == 3) {
                    acc[i][j] = MFMA16(a_h[i], b_l[j], acc[i][j]);
                    acc[i][j] = MFMA16(a_l[i], b_h[j], acc[i][j]);
                }
            }
        __syncthreads();
    }

    const long cbase = z * sC;
    const bool wlo = (Clo != nullptr);
#pragma unroll
    for (int i = 0; i < 4; ++i) {
#pragma unroll
        for (int r = 0; r < 4; ++r) {
            int row = row0 + wr + i * 16 + quad * 4 + r;
#pragma unroll
            for (int j = 0; j < 4; ++j) {
                int col = col0 + wc + j * 16 + mfrag;
                long idx = cbase + (long)row * Ncdim + col;
                float v = acc[i][j][r];
                if constexpr (EPI == 0) {
                    bf16 h = (bf16)v;
                    Chi[idx] = h;
                    if (wlo) Clo[idx] = (bf16)(v - (float)h);
                } else if constexpr (EPI == 1) {
                    Cf[idx] = v;
                } else {
                    Cf[idx] = v;
                    Feat[idx] = v + Text[idx];
                }
            }
        }
    }
}

// ===========================================================================
// 256x256-tile 8-wave GEMMs, round 3: 32x32x16 MFMA (2495 vs 2075 TF ceiling,
// half the MFMA instruction count) on the round-2 pipelined counted-wait
// schedule. Each wave owns 128x64 = 4x2 fragments of 32x32, acc = f32x16.
// Fragment layout (m74/m101 verified): A/B lane l holds row/col = l&31,
// k = (l>>5)*8 + j;  C/D: col = l&31, row = (reg&3) + 8*(reg>>2) + 4*(l>>5).
// LDS swizzle: slot = kb ^ ((row>>1)&3) on 64B rows (BK=32) — granule-
// balanced for the 32-row read pattern (8 hits per 16B-granule per wave64).
// Staging source offsets hoisted out of the K-loop (uniform +BK bump only).
// Numerics: per-accumulator term order (hh, hl, lh; ascending k) preserved.
// ===========================================================================

__device__ __forceinline__ void xcd_swz(int& bx, int& by, int gx, int gy) {
    int nwg = gx * gy;
    int flat = by * gx + bx;
    flat = (flat & 7) * (nwg >> 3) + (flat >> 3);   // bijective: nwg % 8 == 0
    bx = flat % gx;
    by = flat / gx;
}

// ---------------------------------------------------------------------------
// 3-term split-bf16 GEMM, BK=32.
// EPI: 0 = write bf16 hi (+lo if Clo), 1 = write fp32 Cf.
// ---------------------------------------------------------------------------
template<int EPI>
__global__ __launch_bounds__(512) void gemm256_3t(
    const bf16* __restrict__ Ah_g, const bf16* __restrict__ Al_g,
    const bf16* __restrict__ Bh_g, const bf16* __restrict__ Bl_g,
    bf16* __restrict__ Chi, bf16* __restrict__ Clo, float* __restrict__ Cf,
    int Ncdim, int Kdim, long sA, long sB, long sC)
{
    __shared__ __align__(16) bf16 lds[2][4][256 * 32];   // 128 KiB

    const int tid = threadIdx.x;
    const int lane = tid & 63;
    const int wv = tid >> 6;
    const int wrow = (wv >> 2) << 7;      // 0 or 128
    const int wcol = (wv & 3) << 6;       // 0,64,128,192
    const int rl = lane & 31;             // row/col within 32-fragment
    const int hi = lane >> 5;             // k-half selector
    const int sx = (lane >> 1) & 3;       // slot XOR (row parity bits)

    const long z = blockIdx.z;
    int bx = blockIdx.x, by = blockIdx.y;
    xcd_swz(bx, by, gridDim.x, gridDim.y);
    const int row0 = by * 256;
    const int col0 = bx * 256;

    // staging source offsets (thread-invariant; advance base ptr by BK/tile)
    const int sr0 = tid >> 2;
    const long soff0 = (long)sr0 * Kdim + (((tid & 3) ^ ((sr0 >> 1) & 3)) << 3);
    const long soff1 = soff0 + ((long)Kdim << 7);   // row + 128

    const bf16* pAh = Ah_g + z * sA + (long)row0 * Kdim;
    const bf16* pAl = Al_g + z * sA + (long)row0 * Kdim;
    const bf16* pBh = Bh_g + z * sB + (long)col0 * Kdim;
    const bf16* pBl = Bl_g + z * sB + (long)col0 * Kdim;

    // ds_read element offsets (panel-relative, tile-invariant)
    const int rdA0 = (wrow + rl) * 32;
    const int rdB0 = (wcol + rl) * 32;
    const int s0 = (hi ^ sx) << 3;         // ks=0 slot bytes/2
    const int s1 = ((2 + hi) ^ sx) << 3;   // ks=1

    f32x16 acc[4][2] = {};
    const int NT = Kdim >> 5;

    // prologue: stage tile 0 into buf 0
    load_lds16(pAh + soff0, &lds[0][0][tid * 8]);
    load_lds16(pAh + soff1, &lds[0][0][4096 + tid * 8]);
    load_lds16(pBh + soff0, &lds[0][2][tid * 8]);
    load_lds16(pBh + soff1, &lds[0][2][4096 + tid * 8]);
    load_lds16(pAl + soff0, &lds[0][1][tid * 8]);
    load_lds16(pAl + soff1, &lds[0][1][4096 + tid * 8]);
    load_lds16(pBl + soff0, &lds[0][3][tid * 8]);
    load_lds16(pBl + soff1, &lds[0][3][4096 + tid * 8]);
    pAh += 32; pAl += 32; pBh += 32; pBl += 32;

    for (int t = 0; t < NT; ++t) {
        const int cur = t & 1;
        const bf16* LAh = lds[cur][0];
        const bf16* LAl = lds[cur][1];
        const bf16* LBh = lds[cur][2];
        const bf16* LBl = lds[cur][3];
        bf16* SAh = lds[cur ^ 1][0];
        bf16* SAl = lds[cur ^ 1][1];
        bf16* SBh = lds[cur ^ 1][2];
        bf16* SBl = lds[cur ^ 1][3];
        const bool pf = (t + 1 < NT);

        // own stages drained; barrier publishes everyone's.
        WAITV0();
        BARRIER();

        bf16x8 ah[4][2], bh[2][2], bl[2][2], al[2][2];
#pragma unroll
        for (int i = 0; i < 4; ++i) {
            ah[i][0] = *(const bf16x8*)(LAh + rdA0 + i * 1024 + s0);
            ah[i][1] = *(const bf16x8*)(LAh + rdA0 + i * 1024 + s1);
        }
#pragma unroll
        for (int j = 0; j < 2; ++j) {
            bh[j][0] = *(const bf16x8*)(LBh + rdB0 + j * 1024 + s0);
            bh[j][1] = *(const bf16x8*)(LBh + rdB0 + j * 1024 + s1);
        }

        // M1: hh, rowblocks 0-1
        __builtin_amdgcn_s_setprio(1);
#pragma unroll
        for (int i = 0; i < 2; ++i)
#pragma unroll
            for (int j = 0; j < 2; ++j)
#pragma unroll
                for (int ks = 0; ks < 2; ++ks)
                    acc[i][j] = MFMA32(ah[i][ks], bh[j][ks], acc[i][j]);
        __builtin_amdgcn_s_setprio(0);

        if (pf) {
            load_lds16(pAh + soff0, SAh + tid * 8);
            load_lds16(pAh + soff1, SAh + 4096 + tid * 8);
            load_lds16(pBh + soff0, SBh + tid * 8);
            load_lds16(pBh + soff1, SBh + 4096 + tid * 8);
        }

#pragma unroll
        for (int j = 0; j < 2; ++j) {
            bl[j][0] = *(const bf16x8*)(LBl + rdB0 + j * 1024 + s0);
            bl[j][1] = *(const bf16x8*)(LBl + rdB0 + j * 1024 + s1);
        }

        // M2: hh, rowblocks 2-3
        __builtin_amdgcn_s_setprio(1);
#pragma unroll
        for (int i = 0; i < 2; ++i)
#pragma unroll
            for (int j = 0; j < 2; ++j)
#pragma unroll
                for (int ks = 0; ks < 2; ++ks)
                    acc[2 + i][j] = MFMA32(ah[2 + i][ks], bh[j][ks], acc[2 + i][j]);
        __builtin_amdgcn_s_setprio(0);

#pragma unroll
        for (int i = 0; i < 2; ++i) {
            al[i][0] = *(const bf16x8*)(LAl + rdA0 + i * 1024 + s0);
            al[i][1] = *(const bf16x8*)(LAl + rdA0 + i * 1024 + s1);
        }

        // M3: hl, rowblocks 0-1
        __builtin_amdgcn_s_setprio(1);
#pragma unroll
        for (int i = 0; i < 2; ++i)
#pragma unroll
            for (int j = 0; j < 2; ++j)
#pragma unroll
                for (int ks = 0; ks < 2; ++ks)
                    acc[i][j] = MFMA32(ah[i][ks], bl[j][ks], acc[i][j]);
        __builtin_amdgcn_s_setprio(0);

        if (pf) {
            load_lds16(pAl + soff0, SAl + tid * 8);
            load_lds16(pAl + soff1, SAl + 4096 + tid * 8);
            load_lds16(pBl + soff0, SBl + tid * 8);
            load_lds16(pBl + soff1, SBl + 4096 + tid * 8);
        }

        // M4: lh, rowblocks 0-1 (uses al[0..1])
        __builtin_amdgcn_s_setprio(1);
#pragma unroll
        for (int i = 0; i < 2; ++i)
#pragma unroll
            for (int j = 0; j < 2; ++j)
#pragma unroll
                for (int ks = 0; ks < 2; ++ks)
                    acc[i][j] = MFMA32(al[i][ks], bh[j][ks], acc[i][j]);
        __builtin_amdgcn_s_setprio(0);

        // al <- rowblocks 2-3
#pragma unroll
        for (int i = 0; i < 2; ++i) {
            al[i][0] = *(const bf16x8*)(LAl + rdA0 + (2 + i) * 1024 + s0);
            al[i][1] = *(const bf16x8*)(LAl + rdA0 + (2 + i) * 1024 + s1);
        }

        // M5: hl rowblocks 2-3 ; M6: lh rowblocks 2-3
        __builtin_amdgcn_s_setprio(1);
#pragma unroll
        for (int i = 0; i < 2; ++i)
#pragma unroll
            for (int j = 0; j < 2; ++j)
#pragma unroll
                for (int ks = 0; ks < 2; ++ks)
                    acc[2 + i][j] = MFMA32(ah[2 + i][ks], bl[j][ks], acc[2 + i][j]);
#pragma unroll
        for (int i = 0; i < 2; ++i)
#pragma unroll
            for (int j = 0; j < 2; ++j)
#pragma unroll
                for (int ks = 0; ks < 2; ++ks)
                    acc[2 + i][j] = MFMA32(al[i][ks], bh[j][ks], acc[2 + i][j]);
        __builtin_amdgcn_s_setprio(0);

        pAh += 32; pAl += 32; pBh += 32; pBl += 32;
    }

    // ---- epilogue ---- C/D: col = l&31, row = (r&3) + 8*(r>>2) + 4*(l>>5)
    const long cbase = z * sC;
    const bool wlo = (Clo != nullptr);
#pragma unroll
    for (int i = 0; i < 4; ++i) {
#pragma unroll
        for (int j = 0; j < 2; ++j) {
            int col = col0 + wcol + j * 32 + rl;
#pragma unroll
            for (int r = 0; r < 16; ++r) {
                int row = row0 + wrow + i * 32 + (r & 3) + ((r >> 2) << 3) + (hi << 2);
                long idx = cbase + (long)row * Ncdim + col;
                float v = acc[i][j][r];
                if constexpr (EPI == 0) {
                    bf16 h = (bf16)v;
                    Chi[idx] = h;
                    if (wlo) Clo[idx] = (bf16)(v - (float)h);
                } else {
                    Cf[idx] = v;
                }
            }
        }
    }
}

// ---------------------------------------------------------------------------
// 1-term GEMM, BK=64, 32x32x16 MFMA, 2-cluster pipelined schedule.
// EPI: 0 = write bf16 hi ; 2 = PV epilogue (Cf = C fp32, Feat = C + Text).
// ---------------------------------------------------------------------------
template<int EPI>
__global__ __launch_bounds__(512) void gemm256_1t(
    const bf16* __restrict__ A_g, const bf16* __restrict__ B_g,
    bf16* __restrict__ Chi, float* __restrict__ Cf,
    const float* __restrict__ Text, float* __restrict__ Feat,
    int Ncdim, int Kdim, long sA, long sB, long sC)
{
    __shared__ __align__(16) bf16 lds[2][2][256 * 64];   // 128 KiB

    const int tid = threadIdx.x;
    const int lane = tid & 63;
    const int wv = tid >> 6;
    const int wrow = (wv >> 2) << 7;
    const int wcol = (wv & 3) << 6;
    const int rl = lane & 31;
    const int hi = lane >> 5;
    const int sx8 = lane & 7;             // slot XOR for 128B rows

    const long z = blockIdx.z;
    int bx = blockIdx.x, by = blockIdx.y;
    xcd_swz(bx, by, gridDim.x, gridDim.y);
    const int row0 = by * 256;
    const int col0 = bx * 256;

    // staging: 4 chunks/panel; rows c*64 + (tid>>3), slot tid&7
    const long soffS = (long)(tid >> 3) * Kdim + ((((tid & 7) ^ ((tid >> 3) & 7))) << 3);
    const long sstep = (long)Kdim << 6;   // +64 rows per chunk

    const bf16* pA = A_g + z * sA + (long)row0 * Kdim;
    const bf16* pB = B_g + z * sB + (long)col0 * Kdim;

    const int rdA0 = (wrow + rl) * 64;
    const int rdB0 = (wcol + rl) * 64;
    int sl[4];
#pragma unroll
    for (int ks = 0; ks < 4; ++ks) sl[ks] = ((ks * 2 + hi) ^ sx8) << 3;

    f32x16 acc[4][2] = {};
    const int NT = Kdim >> 6;

    // prologue
#pragma unroll
    for (int c = 0; c < 4; ++c) {
        load_lds16(pA + soffS + c * sstep, &lds[0][0][c * 4096 + tid * 8]);
        load_lds16(pB + soffS + c * sstep, &lds[0][1][c * 4096 + tid * 8]);
    }
    pA += 64; pB += 64;

    for (int t = 0; t < NT; ++t) {
        const int cur = t & 1;
        const bf16* LA = lds[cur][0];
        const bf16* LB = lds[cur][1];
        bf16* SA = lds[cur ^ 1][0];
        bf16* SB = lds[cur ^ 1][1];
        const bool pf = (t + 1 < NT);

        WAITV0();
        BARRIER();

        bf16x8 a[2][4], b[2][4];
#pragma unroll
        for (int ii = 0; ii < 2; ++ii)
#pragma unroll
            for (int ks = 0; ks < 4; ++ks)
                a[ii][ks] = *(const bf16x8*)(LA + rdA0 + ii * 2048 + sl[ks]);
#pragma unroll
        for (int j = 0; j < 2; ++j)
#pragma unroll
            for (int ks = 0; ks < 4; ++ks)
                b[j][ks] = *(const bf16x8*)(LB + rdB0 + j * 2048 + sl[ks]);

        // M1: rowblocks 0-1
        __builtin_amdgcn_s_setprio(1);
#pragma unroll
        for (int ii = 0; ii < 2; ++ii)
#pragma unroll
            for (int j = 0; j < 2; ++j)
#pragma unroll
                for (int ks = 0; ks < 4; ++ks)
                    acc[ii][j] = MFMA32(a[ii][ks], b[j][ks], acc[ii][j]);
        __builtin_amdgcn_s_setprio(0);

        if (pf) {
#pragma unroll
            for (int c = 0; c < 4; ++c)
                load_lds16(pA + soffS + c * sstep, SA + c * 4096 + tid * 8);
        }

        // a <- rowblocks 2-3
#pragma unroll
        for (int ii = 0; ii < 2; ++ii)
#pragma unroll
            for (int ks = 0; ks < 4; ++ks)
                a[ii][ks] = *(const bf16x8*)(LA + rdA0 + (2 + ii) * 2048 + sl[ks]);

        // M2: rowblocks 2-3
        __builtin_amdgcn_s_setprio(1);
#pragma unroll
        for (int ii = 0; ii < 2; ++ii)
#pragma unroll
            for (int j = 0; j < 2; ++j)
#pragma unroll
                for (int ks = 0; ks < 4; ++ks)
                    acc[2 + ii][j] = MFMA32(a[ii][ks], b[j][ks], acc[2 + ii][j]);
        __builtin_amdgcn_s_setprio(0);

        if (pf) {
#pragma unroll
            for (int c = 0; c < 4; ++c)
                load_lds16(pB + soffS + c * sstep, SB + c * 4096 + tid * 8);
        }

        pA += 64; pB += 64;
    }

    // ---- epilogue ----
    const long cbase = z * sC;
#pragma unroll
    for (int i = 0; i < 4; ++i) {
#pragma unroll
        for (int j = 0; j < 2; ++j) {
            int col = col0 + wcol + j * 32 + rl;
#pragma unroll
            for (int r = 0; r < 16; ++r) {
                int row = row0 + wrow + i * 32 + (r & 3) + ((r >> 2) << 3) + (hi << 2);
                long idx = cbase + (long)row * Ncdim + col;
                float v = acc[i][j][r];
                if constexpr (EPI == 0) {
                    Chi[idx] = (bf16)v;
                } else {
                    Cf[idx] = v;
                    Feat[idx] = v + Text[idx];
                }
            }
        }
    }
}

// ---------------------------------------------------------------------------
// Column softmax over the QUERY axis (round-4 verified).
// ---------------------------------------------------------------------------
__global__ __launch_bounds__(1024) void col_softmax_bf16(const float* __restrict__ S,
                                                         bf16* __restrict__ Aout)
{
    const int b = blockIdx.x / (N / 64);
    const int mbase = (blockIdx.x % (N / 64)) * 64;
    const int t = threadIdx.x;
    const int mloc = t & 63;
    const int slice = t >> 6;
    const int m = mbase + mloc;
    const float* Sb = S + (size_t)b * N * N;
    bf16* Ab = Aout + (size_t)b * N * N;
    const int n_lo = slice * (N / 16), n_hi = n_lo + (N / 16);

    __shared__ float red_m[16][64];
    __shared__ float red_s[16][64];

    float mx = -INFINITY, s = 0.0f;
    for (int n = n_lo; n < n_hi; n += 8) {
        float x[8];
#pragma unroll
        for (int u = 0; u < 8; ++u) x[u] = Sb[(size_t)(n + u) * N + m];
        float bm = x[0];
#pragma unroll
        for (int u = 1; u < 8; ++u) bm = fmaxf(bm, x[u]);
        float nm = fmaxf(mx, bm);
        float a = 0.0f;
#pragma unroll
        for (int u = 0; u < 8; ++u) a += __expf(x[u] - nm);
        s = s * __expf(mx - nm) + a;
        mx = nm;
    }
    red_m[slice][mloc] = mx;
    red_s[slice][mloc] = s;
    __syncthreads();

    float gm = -INFINITY;
#pragma unroll
    for (int i = 0; i < 16; ++i) gm = fmaxf(gm, red_m[i][mloc]);
    float den = 0.0f;
#pragma unroll
    for (int i = 0; i < 16; ++i) den += red_s[i][mloc] * __expf(red_m[i][mloc] - gm);
    float inv = 1.0f / den;

    for (int n = n_lo; n < n_hi; n += 8) {
        float x[8];
#pragma unroll
        for (int u = 0; u < 8; ++u) x[u] = Sb[(size_t)(n + u) * N + m];
#pragma unroll
        for (int u = 0; u < 8; ++u)
            Ab[(size_t)(n + u) * N + m] = (bf16)(__expf(x[u] - gm) * inv);
    }
}

// ---------------------------------------------------------------------------
extern "C" void kernel_launch(void* const* d_in, const int* in_sizes, int n_in,
                              void* d_out, int out_size, void* d_ws, size_t ws_size,
                              hipStream_t stream)
{
    const float* img  = (const float*)d_in[0];
    const float* text = (const float*)d_in[1];
    const float* Wq   = (const float*)d_in[2];
    const float* Wk   = (const float*)d_in[3];
    const float* Wv   = (const float*)d_in[4];

    const long E  = (long)B * N * D;   // 16.78M
    const long W2 = (long)D * D;       // 1.05M
    const long EN = (long)B * N * N;   // 33.55M

    // ws layout identical to the verified round-1 plan (201.3 MB).
    char* ws = (char*)d_ws;
    float* S     = (float*)ws;
    bf16* img_h  = (bf16*)ws;
    bf16* img_l  = img_h + E;
    bf16* WqT_h  = (bf16*)(ws + (size_t)4 * E);
    bf16* WqT_l  = WqT_h + W2;
    bf16* WkT_h  = WqT_l + W2;
    bf16* WkT_l  = WkT_h + W2;
    bf16* Wqk_h  = WkT_l + W2;
    bf16* Wqk_l  = Wqk_h + W2;
    bf16* Wv_l_s = Wqk_l + W2;
    float* out_pv = (float*)ws;            // S region, dead after softmax

    bf16* text_h = (bf16*)(ws + (size_t)EN * 4);
    bf16* text_l = text_h + E;
    bf16* VT_h   = text_l;                 // recycled after S GEMM

    bf16* T_h  = (bf16*)d_out;
    bf16* T_l  = T_h + E;
    bf16* Wv_h = T_l + E;
    bf16* alpha = (bf16*)d_out;
    float* out  = (float*)d_out;
    float* feat = out + E;

    dim3 blk(256);
    dim3 blk5(512);

    // 1. splits
    split_fp32<<<E / 1024, blk, 0, stream>>>(img,  img_h,  img_l,  E);
    split_fp32<<<E / 1024, blk, 0, stream>>>(text, text_h, text_l, E);
    split_fp32<<<W2 / 1024, blk, 0, stream>>>(Wv, Wv_h, Wv_l_s, W2);
    tsplit_1024<<<dim3(16, 16), blk, 0, stream>>>(Wq, WqT_h, WqT_l);
    tsplit_1024<<<dim3(16, 16), blk, 0, stream>>>(Wk, WkT_h, WkT_l);

    // 2. Wqk'[i,j] = sum_k Wk[k,i] * Wq[k,j]  (tiny: stay on 128^2 kernel)
    gemm_nt_mfma<3, 0><<<dim3(8, 8, 1), blk, 0, stream>>>(
        WkT_h, WkT_l, WqT_h, WqT_l, Wqk_h, Wqk_l, nullptr, nullptr, nullptr,
        D, D, D, 0, 0, 0);

    // 3. T = img @ Wqk  (split out to T_h/T_l in d_out)
    gemm256_3t<0><<<dim3(D / 256, (B * N) / 256, 1), blk5, 0, stream>>>(
        img_h, img_l, Wqk_h, Wqk_l, T_h, T_l, nullptr,
        D, D, 0, 0, 0);

    // 4. S[b] = T[b] @ text[b]^T  (3-term, fp32)
    gemm256_3t<1><<<dim3(N / 256, N / 256, B), blk5, 0, stream>>>(
        T_h, T_l, text_h, text_l, nullptr, nullptr, S,
        N, D, (long)N * D, (long)N * D, (long)N * N);

    // 5. VT[b][v][m] = sum_d Wv[v,d] * text[b,m,d]
    gemm256_1t<0><<<dim3(N / 256, D / 256, B), blk5, 0, stream>>>(
        Wv_h, text_h, VT_h, nullptr, nullptr, nullptr,
        N, D, 0, (long)N * D, (long)D * N);

    // 6. softmax over query axis; S fp32 -> alpha bf16
    col_softmax_bf16<<<dim3(B * N / 64), dim3(1024), 0, stream>>>(S, alpha);

    // 7. out = alpha @ VT^T ; feat = out + text
    gemm256_1t<2><<<dim3(D / 256, N / 256, B), blk5, 0, stream>>>(
        alpha, VT_h, nullptr, out_pv, text, feat,
        D, N, (long)N * N, (long)D * N, (long)N * D);

    // 8. move `out` home (alpha occupied d_out[0..4E) during PV)
    hipMemcpyAsync(out, out_pv, (size_t)E * 4, hipMemcpyDeviceToDevice, stream);
}